// Round 1
// baseline (651.513 us; speedup 1.0000x reference)
//
#include <hip/hip_runtime.h>

#define B_ 64
#define L_ 4096
#define N_ 128
#define F_ 2049
#define M_ 2048   // packed complex FFT size (L/2)

// ---------------------------------------------------------------------------
// Stockham radix-2 DIF complex FFT, 2048 points, 256 threads, self-sorting.
// tw[k] = (cos(2pi k/2048), sin(2pi k/2048)); sign<0 => forward (e^{-i}),
// sign>0 => unnormalized inverse (e^{+i}). Result buffer returned via *res.
// Caller must __syncthreads() before calling (input buffer fully written).
// ---------------------------------------------------------------------------
static __device__ __forceinline__ void fft_stages(float2* bufA, float2* bufB,
                                                  const float2* tw, int t,
                                                  int sign, float2** res) {
  float2* src = bufA;
  float2* dst = bufB;
  for (int s = 0; s < 11; ++s) {
#pragma unroll
    for (int jj = 0; jj < 4; ++jj) {
      int j = t + jj * 256;           // 0..1023 butterfly id
      int p = j >> s;
      int q = j & ((1 << s) - 1);
      float2 a = src[j];              // == src[q + (1<<s)*p]
      float2 b = src[j + 1024];       // == src[q + (1<<s)*(p+mhalf)]
      float2 w = tw[p << s];
      float wr = w.x;
      float wi = (sign < 0) ? -w.y : w.y;
      float sr = a.x - b.x, si = a.y - b.y;
      int d0 = q + ((2 * p) << s);
      dst[d0] = make_float2(a.x + b.x, a.y + b.y);
      dst[d0 + (1 << s)] = make_float2(sr * wr - si * wi, sr * wi + si * wr);
    }
    __syncthreads();
    float2* tmp = src; src = dst; dst = tmp;
  }
  *res = src;  // 11 stages -> ends in bufB
}

static __device__ __forceinline__ void make_twiddles(float2* tw, int t) {
  for (int k = t; k < 1024; k += 256) {
    float ang = (float)k * 0.00306796157577128235f;  // 2*pi/2048
    float sv, cv;
    sincosf(ang, &sv, &cv);
    tw[k] = make_float2(cv, sv);
  }
}

// ---------------------------------------------------------------------------
// Tiled transpose per batch: in [R,C] -> out [C,R].  grid (C/32, R/32, B)
// ---------------------------------------------------------------------------
__global__ __launch_bounds__(256) void transpose_k(const float* __restrict__ in,
                                                   float* __restrict__ out,
                                                   int R, int C) {
  __shared__ float tile[32][33];
  const float* ip = in + (size_t)blockIdx.z * R * C;
  float* op = out + (size_t)blockIdx.z * R * C;
  int c0 = blockIdx.x * 32;
  int r0 = blockIdx.y * 32;
  int x = threadIdx.x;   // 0..31
  int y = threadIdx.y;   // 0..7
#pragma unroll
  for (int i = 0; i < 4; ++i)
    tile[y + 8 * i][x] = ip[(size_t)(r0 + y + 8 * i) * C + (c0 + x)];
  __syncthreads();
#pragma unroll
  for (int i = 0; i < 4; ++i)
    op[(size_t)(c0 + y + 8 * i) * R + (r0 + x)] = tile[x][y + 8 * i];
}

// ---------------------------------------------------------------------------
// P1: per-(b,n) forward rfft, accumulate |X_f| into magsum[b,f].
// S = element stride of the signal (1 for transposed staging, N_ for direct).
// ---------------------------------------------------------------------------
template <int S>
__global__ __launch_bounds__(256) void p1_fft_mag(const float* __restrict__ src,
                                                  float* __restrict__ magsum) {
  __shared__ float2 bufA[M_];
  __shared__ float2 bufB[M_];
  __shared__ float2 tw[M_ / 2];
  int t = threadIdx.x;
  int blk = blockIdx.x;
  int b = blk >> 7;
  int n = blk & 127;
  const float* base = (S == 1) ? (src + (size_t)blk * L_)
                               : (src + (size_t)b * L_ * N_ + n);
  make_twiddles(tw, t);
  if (S == 1) {
    const float2* r2 = (const float2*)base;
#pragma unroll
    for (int jj = 0; jj < 8; ++jj) bufA[t + jj * 256] = r2[t + jj * 256];
  } else {
#pragma unroll
    for (int jj = 0; jj < 8; ++jj) {
      int k = t + jj * 256;
      bufA[k] = make_float2(base[(size_t)(2 * k) * S],
                            base[(size_t)(2 * k + 1) * S]);
    }
  }
  __syncthreads();
  float2* Z;
  fft_stages(bufA, bufB, tw, t, -1, &Z);

  // Unpack real-FFT bins: X[f] = A + e^{-2pi i f/L} B
  float* msum = magsum + (size_t)b * F_;
  for (int f = t; f <= 2048; f += 256) {
    float mg;
    if (f == 0) {
      float2 z = Z[0]; mg = fabsf(z.x + z.y);
    } else if (f == 2048) {
      float2 z = Z[0]; mg = fabsf(z.x - z.y);
    } else {
      float2 zf = Z[f], zm = Z[M_ - f];
      float Are = 0.5f * (zf.x + zm.x), Aim = 0.5f * (zf.y - zm.y);
      float Bre = 0.5f * (zf.y + zm.y), Bim = -0.5f * (zf.x - zm.x);
      float ang = (float)f * 0.00153398078788564117f;  // pi/2048 = 2pi f / L
      float sv, cv;
      __sincosf(ang, &sv, &cv);
      float Xre = Are + cv * Bre + sv * Bim;
      float Xim = Aim + cv * Bim - sv * Bre;
      mg = sqrtf(Xre * Xre + Xim * Xim);
    }
    atomicAdd(&msum[f], mg);
  }
}

// ---------------------------------------------------------------------------
// G1: hsum[b,o] = sum_i (magsum[b,i]/128) * W1[i,o]   (split-K, atomics)
// grid (17, 16), 128 threads; each thread owns one o, 64 batch accumulators.
// ---------------------------------------------------------------------------
__global__ __launch_bounds__(128) void g1_gemm(const float* __restrict__ mag,
                                               const float* __restrict__ W1,
                                               float* __restrict__ hsum) {
  __shared__ float mt[64][72];  // [ii][b], row stride 72 floats (16B-aligned rows)
  int o = blockIdx.x * 128 + threadIdx.x;
  int i0 = blockIdx.y * 129;
  int i1 = min(F_, i0 + 129);
  float acc[64];
#pragma unroll
  for (int b = 0; b < 64; ++b) acc[b] = 0.f;
  for (int ic = i0; ic < i1; ic += 64) {
    int nn = min(64, i1 - ic);
    for (int idx = threadIdx.x; idx < 64 * 64; idx += 128) {
      int bb = idx >> 6, ii = idx & 63;   // ii fast -> coalesced mag reads
      mt[ii][bb] = (ii < nn) ? mag[bb * F_ + ic + ii] * (1.0f / 128.0f) : 0.f;
    }
    __syncthreads();
    if (o < F_) {
      for (int ii = 0; ii < nn; ++ii) {
        float w = W1[(size_t)(ic + ii) * F_ + o];
        const float4* m4 = (const float4*)&mt[ii][0];
#pragma unroll
        for (int b4 = 0; b4 < 16; ++b4) {
          float4 m = m4[b4];
          acc[4 * b4 + 0] += m.x * w;
          acc[4 * b4 + 1] += m.y * w;
          acc[4 * b4 + 2] += m.z * w;
          acc[4 * b4 + 3] += m.w * w;
        }
      }
    }
    __syncthreads();
  }
  if (o < F_) {
#pragma unroll
    for (int b = 0; b < 64; ++b) atomicAdd(&hsum[(size_t)b * F_ + o], acc[b]);
  }
}

// ---------------------------------------------------------------------------
// G2: per-batch block. logits = relu(hsum+b1) @ W2 + b2 -> softmax -> weights;
// band boundaries -> idx; write wmask[b,f] = w[band(f)].
// ---------------------------------------------------------------------------
__global__ __launch_bounds__(256) void g2_gate(const float* __restrict__ hsum,
                                               const float* __restrict__ gb1,
                                               const float* __restrict__ W2,
                                               const float* __restrict__ gb2,
                                               const float* __restrict__ bbs,
                                               float* __restrict__ wmask) {
  __shared__ float red[256 * 8];
  __shared__ float wsm[8];
  __shared__ int idxs[9];
  int b = blockIdx.x;
  int t = threadIdx.x;
  float p[8];
#pragma unroll
  for (int e = 0; e < 8; ++e) p[e] = 0.f;
  for (int o = t; o < F_; o += 256) {
    float hv = hsum[(size_t)b * F_ + o] + gb1[o];
    hv = fmaxf(hv, 0.f);
    const float4* w2p = (const float4*)(W2 + (size_t)o * 8);
    float4 wa = w2p[0], wb = w2p[1];
    p[0] += hv * wa.x; p[1] += hv * wa.y; p[2] += hv * wa.z; p[3] += hv * wa.w;
    p[4] += hv * wb.x; p[5] += hv * wb.y; p[6] += hv * wb.z; p[7] += hv * wb.w;
  }
#pragma unroll
  for (int e = 0; e < 8; ++e) red[t * 8 + e] = p[e];
  __syncthreads();
  for (int s = 128; s >= 1; s >>= 1) {
    if (t < s) {
#pragma unroll
      for (int e = 0; e < 8; ++e) red[t * 8 + e] += red[(t + s) * 8 + e];
    }
    __syncthreads();
  }
  if (t == 0) {
    float lg[8];
    float mx = -1e30f;
#pragma unroll
    for (int e = 0; e < 8; ++e) { lg[e] = red[e] + gb2[e]; mx = fmaxf(mx, lg[e]); }
    float sm = 0.f;
#pragma unroll
    for (int e = 0; e < 8; ++e) { lg[e] = expf(lg[e] - mx); sm += lg[e]; }
    float inv = 1.f / sm;
#pragma unroll
    for (int e = 0; e < 8; ++e) wsm[e] = lg[e] * inv;
    // sigmoid -> sort -> integer bin boundaries (match f32 reference path)
    float bv[7];
#pragma unroll
    for (int k = 0; k < 7; ++k) bv[k] = 1.f / (1.f + expf(-bbs[k]));
    for (int a = 1; a < 7; ++a) {
      float v = bv[a];
      int j = a - 1;
      while (j >= 0 && bv[j] > v) { bv[j + 1] = bv[j]; --j; }
      bv[j + 1] = v;
    }
    idxs[0] = 0;
    idxs[8] = F_;
    for (int k = 0; k < 7; ++k) {
      int v = (int)(bv[k] * (float)F_);   // trunc, matches .astype(int32)
      v = min(max(v, 0), F_);
      idxs[k + 1] = v;
    }
  }
  __syncthreads();
  for (int f = t; f < F_; f += 256) {
    float wv = 0.f;
#pragma unroll
    for (int e = 0; e < 8; ++e)
      if (f >= idxs[e] && f < idxs[e + 1]) wv = wsm[e];
    wmask[(size_t)b * F_ + f] = wv;
  }
}

// ---------------------------------------------------------------------------
// P3: out_row = irfft( rfft(row) * (1 + sqrt(var)*wmask) ) + mean
// (residual folded: xN + x_rec == irfft(X*(1+s*wm)) + mean, since
//  xN == irfft(rfft(xN)) exactly)
// ---------------------------------------------------------------------------
template <int S>
__global__ __launch_bounds__(256) void p3_filter(const float* __restrict__ src,
                                                 const float* __restrict__ wmask,
                                                 float* __restrict__ dstp) {
  __shared__ float2 bufA[M_];
  __shared__ float2 bufB[M_];
  __shared__ float2 tw[M_ / 2];
  __shared__ float red[512];
  __shared__ float sstat[2];
  int t = threadIdx.x;
  int blk = blockIdx.x;
  int b = blk >> 7;
  int n = blk & 127;
  const float* base = (S == 1) ? (src + (size_t)blk * L_)
                               : (src + (size_t)b * L_ * N_ + n);
  float* obase = (S == 1) ? (dstp + (size_t)blk * L_)
                          : (dstp + (size_t)b * L_ * N_ + n);
  make_twiddles(tw, t);
  float lsum = 0.f, lsq = 0.f;
  if (S == 1) {
    const float2* r2 = (const float2*)base;
#pragma unroll
    for (int jj = 0; jj < 8; ++jj) {
      float2 v = r2[t + jj * 256];
      bufA[t + jj * 256] = v;
      lsum += v.x + v.y;
      lsq += v.x * v.x + v.y * v.y;
    }
  } else {
#pragma unroll
    for (int jj = 0; jj < 8; ++jj) {
      int k = t + jj * 256;
      float2 v = make_float2(base[(size_t)(2 * k) * S],
                             base[(size_t)(2 * k + 1) * S]);
      bufA[k] = v;
      lsum += v.x + v.y;
      lsq += v.x * v.x + v.y * v.y;
    }
  }
  red[t] = lsum;
  red[t + 256] = lsq;
  __syncthreads();
  for (int s2 = 128; s2 >= 1; s2 >>= 1) {
    if (t < s2) { red[t] += red[t + s2]; red[t + 256] += red[t + 256 + s2]; }
    __syncthreads();
  }
  if (t == 0) {
    float mean = red[0] * (1.0f / 4096.0f);
    float var = red[256] * (1.0f / 4096.0f) - mean * mean + 1e-6f;
    sstat[0] = mean;
    sstat[1] = sqrtf(var);
  }
  __syncthreads();
  float2* Z;
  fft_stages(bufA, bufB, tw, t, -1, &Z);   // Z = bufB
  float mean = sstat[0], sdv = sstat[1];
  const float* wm = wmask + (size_t)b * F_;
  float2* Zp = (Z == bufA) ? bufB : bufA;  // bufA

  // Repack: X'[f] = (1+s*wm[f])*X[f]; rebuild packed spectrum Z'.
  for (int f = t; f < 1024; f += 256) {
    if (f == 0) {
      float2 z0 = Z[0];
      float X0 = (z0.x + z0.y) * (1.f + sdv * wm[0]);
      float XM = (z0.x - z0.y) * (1.f + sdv * wm[2048]);
      Zp[0] = make_float2(0.5f * (X0 + XM), 0.5f * (X0 - XM));
      float2 zc = Z[1024];
      float mc = 1.f + sdv * wm[1024];     // Z'[1024] = m * Z[1024]
      Zp[1024] = make_float2(zc.x * mc, zc.y * mc);
    } else {
      float2 zf = Z[f], zm = Z[M_ - f];
      float Are = 0.5f * (zf.x + zm.x), Aim = 0.5f * (zf.y - zm.y);
      float Bre = 0.5f * (zf.y + zm.y), Bim = -0.5f * (zf.x - zm.x);
      float ang = (float)f * 0.00153398078788564117f;  // 2pi f / L
      float sv, cv;
      __sincosf(ang, &sv, &cv);
      float WBre = cv * Bre + sv * Bim;  // W = (c,-s)
      float WBim = cv * Bim - sv * Bre;
      float Xre = Are + WBre, Xim = Aim + WBim;          // X[f]
      float Xmre = Are - WBre, Xmim = -(Aim - WBim);     // X[M-f] = conj(A-WB)
      float mf = 1.f + sdv * wm[f];
      float mg = 1.f + sdv * wm[M_ - f];
      Xre *= mf; Xim *= mf;
      Xmre *= mg; Xmim *= mg;
      // Z'[f] = A' + i B',  A' = (X'+conj(Xm'))/2, B' = conj(W)*(X'-conj(Xm'))/2
      float Apre = 0.5f * (Xre + Xmre), Apim = 0.5f * (Xim - Xmim);
      float Tre = 0.5f * (Xre - Xmre), Tim = 0.5f * (Xim + Xmim);
      float Bpre = cv * Tre - sv * Tim;
      float Bpim = cv * Tim + sv * Tre;
      Zp[f] = make_float2(Apre - Bpim, Apim + Bpre);
      // Z'[M-f]: A'g=(Xm'+conj(X'))/2, B'g = -W*(Xm'-conj(X'))/2
      float Agre = 0.5f * (Xmre + Xre), Agim = 0.5f * (Xmim - Xim);
      float Tgre = 0.5f * (Xmre - Xre), Tgim = 0.5f * (Xmim + Xim);
      float Bgre = -(cv * Tgre + sv * Tgim);
      float Bgim = -(cv * Tgim - sv * Tgre);
      Zp[M_ - f] = make_float2(Agre - Bgim, Agim + Bgre);
    }
  }
  __syncthreads();
  float2* zr;
  fft_stages(Zp, Z, tw, t, 1, &zr);  // unnormalized inverse
  const float inv = 1.0f / 2048.0f;
  if (S == 1) {
    float2* o2 = (float2*)obase;
#pragma unroll
    for (int jj = 0; jj < 8; ++jj) {
      int k = t + jj * 256;
      float2 z = zr[k];
      o2[k] = make_float2(z.x * inv + mean, z.y * inv + mean);
    }
  } else {
#pragma unroll
    for (int jj = 0; jj < 8; ++jj) {
      int k = t + jj * 256;
      float2 z = zr[k];
      obase[(size_t)(2 * k) * S] = z.x * inv + mean;
      obase[(size_t)(2 * k + 1) * S] = z.y * inv + mean;
    }
  }
}

// ---------------------------------------------------------------------------
extern "C" void kernel_launch(void* const* d_in, const int* in_sizes, int n_in,
                              void* d_out, int out_size, void* d_ws,
                              size_t ws_size, hipStream_t stream) {
  const float* x = (const float*)d_in[0];
  const float* bbs = (const float*)d_in[1];
  const float* W1 = (const float*)d_in[2];
  const float* gb1 = (const float*)d_in[3];
  const float* W2 = (const float*)d_in[4];
  const float* gb2 = (const float*)d_in[5];
  float* out = (float*)d_out;

  const size_t bigElems = (size_t)B_ * N_ * L_;              // 33.5M floats
  const size_t smallBytes = (size_t)3 * B_ * F_ * sizeof(float);
  const bool fast = ws_size >= bigElems * sizeof(float) + smallBytes;

  char* smallBase = (char*)d_ws + (fast ? bigElems * sizeof(float) : 0);
  float* magsum = (float*)smallBase;
  float* hsum = magsum + (size_t)B_ * F_;
  float* wmaskp = hsum + (size_t)B_ * F_;
  float* outT = (float*)d_ws;

  hipMemsetAsync(magsum, 0, (size_t)2 * B_ * F_ * sizeof(float), stream);

  dim3 tb(32, 8);
  if (fast) {
    // stage xT = transpose(x) in d_out (overwritten again by T2 at the end)
    transpose_k<<<dim3(N_ / 32, L_ / 32, B_), tb, 0, stream>>>(x, out, L_, N_);
    p1_fft_mag<1><<<dim3(B_ * N_), 256, 0, stream>>>(out, magsum);
  } else {
    p1_fft_mag<N_><<<dim3(B_ * N_), 256, 0, stream>>>(x, magsum);
  }
  g1_gemm<<<dim3(17, 16), 128, 0, stream>>>(magsum, W1, hsum);
  g2_gate<<<dim3(B_), 256, 0, stream>>>(hsum, gb1, W2, gb2, bbs, wmaskp);
  if (fast) {
    p3_filter<1><<<dim3(B_ * N_), 256, 0, stream>>>(out, wmaskp, outT);
    transpose_k<<<dim3(L_ / 32, N_ / 32, B_), tb, 0, stream>>>(outT, out, N_, L_);
  } else {
    p3_filter<N_><<<dim3(B_ * N_), 256, 0, stream>>>(x, wmaskp, out);
  }
}

// Round 2
// 545.269 us; speedup vs baseline: 1.1948x; 1.1948x over previous
//
#include <hip/hip_runtime.h>

#define B_ 64
#define L_ 4096
#define N_ 128
#define F_ 2049
#define M_ 2048   // packed complex FFT size (L/2)

// padded LDS index: +1 float2 per 8 -> stage-0 scatter lands uniform mod 16
__device__ __forceinline__ int pidx(int a) { return a + (a >> 3); }

__device__ __forceinline__ float2 cadd(float2 a, float2 b) { return make_float2(a.x + b.x, a.y + b.y); }
__device__ __forceinline__ float2 csub(float2 a, float2 b) { return make_float2(a.x - b.x, a.y - b.y); }
__device__ __forceinline__ float2 cmul(float2 a, float2 b) {
  return make_float2(a.x * b.x - a.y * b.y, a.x * b.y + a.y * b.x);
}
template <int SGN>
__device__ __forceinline__ float2 mulsi(float2 a) {  // * (SGN * i)
  return (SGN > 0) ? make_float2(-a.y, a.x) : make_float2(a.y, -a.x);
}

template <int SGN>
__device__ __forceinline__ void dft8(float2* v) {
  const float C = 0.70710678118654752f;
  float2 t0 = cadd(v[0], v[4]), t1 = csub(v[0], v[4]);
  float2 t2 = cadd(v[2], v[6]), t3 = mulsi<SGN>(csub(v[2], v[6]));
  float2 t4 = cadd(v[1], v[5]), t5 = csub(v[1], v[5]);
  float2 t6 = cadd(v[3], v[7]), t7 = mulsi<SGN>(csub(v[3], v[7]));
  float2 u0 = cadd(t0, t2), u1 = csub(t0, t2);
  float2 u2 = cadd(t1, t3), u3 = csub(t1, t3);
  float2 u4 = cadd(t4, t6), u5 = csub(t4, t6);
  float2 u6 = cadd(t5, t7), u7 = csub(t5, t7);
  float2 w1 = make_float2(C, (SGN > 0) ? C : -C);    // e^{s i pi/4}
  float2 w3 = make_float2(-C, (SGN > 0) ? C : -C);   // e^{s i 3pi/4}
  float2 a5 = mulsi<SGN>(u5);
  float2 b6 = cmul(u6, w1);
  float2 b7 = cmul(u7, w3);
  v[0] = cadd(u0, u4); v[4] = csub(u0, u4);
  v[2] = cadd(u1, a5); v[6] = csub(u1, a5);
  v[1] = cadd(u2, b6); v[5] = csub(u2, b6);
  v[3] = cadd(u3, b7); v[7] = csub(u3, b7);
}

template <int SGN>
__device__ __forceinline__ void dft4(float2* v) {
  float2 e0 = cadd(v[0], v[2]), e1 = csub(v[0], v[2]);
  float2 o0 = cadd(v[1], v[3]), o1 = mulsi<SGN>(csub(v[1], v[3]));
  v[0] = cadd(e0, o0); v[2] = csub(e0, o0);
  v[1] = cadd(e1, o1); v[3] = csub(e1, o1);
}

// post-DFT Stockham twiddle: v[k] *= exp(SGN * 2pi i * k * pm / 2048)
template <int SGN>
__device__ __forceinline__ void tw8(float2* v, int pm) {
  float ang = (float)pm * 0.00306796157577128245f;  // 2pi/2048
  float sv, cv;
  __sincosf(ang, &sv, &cv);
  float2 w = make_float2(cv, (SGN > 0) ? sv : -sv);
  float2 wk = w;
  v[1] = cmul(v[1], wk);
#pragma unroll
  for (int k = 2; k < 8; ++k) { wk = cmul(wk, w); v[k] = cmul(v[k], wk); }
}

// 2048-pt complex Stockham FFT, radices 8,8,8,4. 256 threads.
// On entry: v[r] = x[t + 256 r] (natural order). On exit: result in
// buf[pidx(f)] natural order, all threads synced.
template <int SGN>
__device__ __forceinline__ void fft2048(float2* __restrict__ buf, float2* v, int t) {
  // stage0: m=1, p=t, q=0
  dft8<SGN>(v);
  tw8<SGN>(v, t);
  __syncthreads();               // callers' outstanding buf reads drain here
#pragma unroll
  for (int k = 0; k < 8; ++k) buf[pidx(8 * t + k)] = v[k];
  __syncthreads();
  // stage1: m=8
#pragma unroll
  for (int r = 0; r < 8; ++r) v[r] = buf[pidx(t + 256 * r)];
  dft8<SGN>(v);
  tw8<SGN>(v, t & ~7);
  __syncthreads();
  {
    int q = t & 7, p = t >> 3;
#pragma unroll
    for (int k = 0; k < 8; ++k) buf[pidx(q + 8 * (8 * p + k))] = v[k];
  }
  __syncthreads();
  // stage2: m=64
#pragma unroll
  for (int r = 0; r < 8; ++r) v[r] = buf[pidx(t + 256 * r)];
  dft8<SGN>(v);
  tw8<SGN>(v, t & ~63);
  __syncthreads();
  {
    int q = t & 63, p = t >> 6;
#pragma unroll
    for (int k = 0; k < 8; ++k) buf[pidx(q + 64 * (8 * p + k))] = v[k];
  }
  __syncthreads();
  // stage3: radix-4, m=512, p=0 -> twiddle-free; 2 butterflies/thread
  float2 w0[4], w1s[4];
#pragma unroll
  for (int r = 0; r < 4; ++r) {
    w0[r] = buf[pidx(t + 512 * r)];
    w1s[r] = buf[pidx(t + 256 + 512 * r)];
  }
  dft4<SGN>(w0);
  dft4<SGN>(w1s);
  __syncthreads();
#pragma unroll
  for (int k = 0; k < 4; ++k) {
    buf[pidx(t + 512 * k)] = w0[k];
    buf[pidx(t + 256 + 512 * k)] = w1s[k];
  }
  __syncthreads();
}

// ---------------------------------------------------------------------------
// Tiled transpose per batch: in [R,C] -> out [C,R].  grid (C/32, R/32, B)
// ---------------------------------------------------------------------------
__global__ __launch_bounds__(256) void transpose_k(const float* __restrict__ in,
                                                   float* __restrict__ out,
                                                   int R, int C) {
  __shared__ float tile[32][33];
  const float* ip = in + (size_t)blockIdx.z * R * C;
  float* op = out + (size_t)blockIdx.z * R * C;
  int c0 = blockIdx.x * 32;
  int r0 = blockIdx.y * 32;
  int x = threadIdx.x;
  int y = threadIdx.y;
#pragma unroll
  for (int i = 0; i < 4; ++i)
    tile[y + 8 * i][x] = ip[(size_t)(r0 + y + 8 * i) * C + (c0 + x)];
  __syncthreads();
#pragma unroll
  for (int i = 0; i < 4; ++i)
    op[(size_t)(c0 + y + 8 * i) * R + (r0 + x)] = tile[x][y + 8 * i];
}

// ---------------------------------------------------------------------------
// P1: per-(b,n) forward rfft, accumulate |X_f| into magsum[b,f].
// ---------------------------------------------------------------------------
template <int S>
__global__ __launch_bounds__(256) void p1_fft_mag(const float* __restrict__ src,
                                                  float* __restrict__ magsum) {
  __shared__ float2 buf[2304];
  int t = threadIdx.x;
  int blk = blockIdx.x;
  int b = blk >> 7;
  int n = blk & 127;
  const float* base = (S == 1) ? (src + (size_t)blk * L_)
                               : (src + (size_t)b * L_ * N_ + n);
  float2 v[8];
  if (S == 1) {
    const float2* r2 = (const float2*)base;
#pragma unroll
    for (int r = 0; r < 8; ++r) v[r] = r2[t + 256 * r];
  } else {
#pragma unroll
    for (int r = 0; r < 8; ++r) {
      int k = t + 256 * r;
      v[r] = make_float2(base[(size_t)(2 * k) * S], base[(size_t)(2 * k + 1) * S]);
    }
  }
  fft2048<-1>(buf, v, t);

  float* msum = magsum + (size_t)b * F_;
#pragma unroll
  for (int i = 0; i < 8; ++i) {
    int f = t + 256 * i;
    float mg;
    if (f == 0) {
      float2 z = buf[pidx(0)];
      mg = fabsf(z.x + z.y);
      atomicAdd(&msum[2048], fabsf(z.x - z.y));
    } else {
      float2 zf = buf[pidx(f)], zm = buf[pidx(2048 - f)];
      float Are = 0.5f * (zf.x + zm.x), Aim = 0.5f * (zf.y - zm.y);
      float Bre = 0.5f * (zf.y + zm.y), Bim = -0.5f * (zf.x - zm.x);
      float ang = (float)f * 0.00153398078788564117f;  // 2pi f / L
      float sv, cv;
      __sincosf(ang, &sv, &cv);
      float Xre = Are + cv * Bre + sv * Bim;
      float Xim = Aim + cv * Bim - sv * Bre;
      mg = sqrtf(Xre * Xre + Xim * Xim);
    }
    atomicAdd(&msum[f], mg);
  }
}

// ---------------------------------------------------------------------------
// G1: hsum[b,o] = sum_i (magsum[b,i]/128) * W1[i,o]   (split-K, atomics)
// ---------------------------------------------------------------------------
__global__ __launch_bounds__(128) void g1_gemm(const float* __restrict__ mag,
                                               const float* __restrict__ W1,
                                               float* __restrict__ hsum) {
  __shared__ float mt[64][72];
  int o = blockIdx.x * 128 + threadIdx.x;
  int i0 = blockIdx.y * 129;
  int i1 = min(F_, i0 + 129);
  float acc[64];
#pragma unroll
  for (int b = 0; b < 64; ++b) acc[b] = 0.f;
  for (int ic = i0; ic < i1; ic += 64) {
    int nn = min(64, i1 - ic);
    for (int idx = threadIdx.x; idx < 64 * 64; idx += 128) {
      int bb = idx >> 6, ii = idx & 63;
      mt[ii][bb] = (ii < nn) ? mag[bb * F_ + ic + ii] * (1.0f / 128.0f) : 0.f;
    }
    __syncthreads();
    if (o < F_) {
      for (int ii = 0; ii < nn; ++ii) {
        float w = W1[(size_t)(ic + ii) * F_ + o];
        const float4* m4 = (const float4*)&mt[ii][0];
#pragma unroll
        for (int b4 = 0; b4 < 16; ++b4) {
          float4 m = m4[b4];
          acc[4 * b4 + 0] += m.x * w;
          acc[4 * b4 + 1] += m.y * w;
          acc[4 * b4 + 2] += m.z * w;
          acc[4 * b4 + 3] += m.w * w;
        }
      }
    }
    __syncthreads();
  }
  if (o < F_) {
#pragma unroll
    for (int b = 0; b < 64; ++b) atomicAdd(&hsum[(size_t)b * F_ + o], acc[b]);
  }
}

// ---------------------------------------------------------------------------
// G2: gate head + band-boundary mask -> wmask[b,f]
// ---------------------------------------------------------------------------
__global__ __launch_bounds__(256) void g2_gate(const float* __restrict__ hsum,
                                               const float* __restrict__ gb1,
                                               const float* __restrict__ W2,
                                               const float* __restrict__ gb2,
                                               const float* __restrict__ bbs,
                                               float* __restrict__ wmask) {
  __shared__ float red[256 * 8];
  __shared__ float wsm[8];
  __shared__ int idxs[9];
  int b = blockIdx.x;
  int t = threadIdx.x;
  float p[8];
#pragma unroll
  for (int e = 0; e < 8; ++e) p[e] = 0.f;
  for (int o = t; o < F_; o += 256) {
    float hv = hsum[(size_t)b * F_ + o] + gb1[o];
    hv = fmaxf(hv, 0.f);
    const float4* w2p = (const float4*)(W2 + (size_t)o * 8);
    float4 wa = w2p[0], wb = w2p[1];
    p[0] += hv * wa.x; p[1] += hv * wa.y; p[2] += hv * wa.z; p[3] += hv * wa.w;
    p[4] += hv * wb.x; p[5] += hv * wb.y; p[6] += hv * wb.z; p[7] += hv * wb.w;
  }
#pragma unroll
  for (int e = 0; e < 8; ++e) red[t * 8 + e] = p[e];
  __syncthreads();
  for (int s = 128; s >= 1; s >>= 1) {
    if (t < s) {
#pragma unroll
      for (int e = 0; e < 8; ++e) red[t * 8 + e] += red[(t + s) * 8 + e];
    }
    __syncthreads();
  }
  if (t == 0) {
    float lg[8];
    float mx = -1e30f;
#pragma unroll
    for (int e = 0; e < 8; ++e) { lg[e] = red[e] + gb2[e]; mx = fmaxf(mx, lg[e]); }
    float sm = 0.f;
#pragma unroll
    for (int e = 0; e < 8; ++e) { lg[e] = expf(lg[e] - mx); sm += lg[e]; }
    float inv = 1.f / sm;
#pragma unroll
    for (int e = 0; e < 8; ++e) wsm[e] = lg[e] * inv;
    float bv[7];
#pragma unroll
    for (int k = 0; k < 7; ++k) bv[k] = 1.f / (1.f + expf(-bbs[k]));
    for (int a = 1; a < 7; ++a) {
      float v = bv[a];
      int j = a - 1;
      while (j >= 0 && bv[j] > v) { bv[j + 1] = bv[j]; --j; }
      bv[j + 1] = v;
    }
    idxs[0] = 0;
    idxs[8] = F_;
    for (int k = 0; k < 7; ++k) {
      int v = (int)(bv[k] * (float)F_);
      v = min(max(v, 0), F_);
      idxs[k + 1] = v;
    }
  }
  __syncthreads();
  for (int f = t; f < F_; f += 256) {
    float wv = 0.f;
#pragma unroll
    for (int e = 0; e < 8; ++e)
      if (f >= idxs[e] && f < idxs[e + 1]) wv = wsm[e];
    wmask[(size_t)b * F_ + f] = wv;
  }
}

// ---------------------------------------------------------------------------
// P3: out_row = irfft( rfft(row) * (1 + sqrt(var)*wmask) ) + mean
// ---------------------------------------------------------------------------
template <int S>
__global__ __launch_bounds__(256) void p3_filter(const float* __restrict__ src,
                                                 const float* __restrict__ wmask,
                                                 float* __restrict__ dstp) {
  __shared__ float2 buf[2304];
  __shared__ float sstat[2];
  int t = threadIdx.x;
  int blk = blockIdx.x;
  int b = blk >> 7;
  int n = blk & 127;
  const float* base = (S == 1) ? (src + (size_t)blk * L_)
                               : (src + (size_t)b * L_ * N_ + n);
  float* obase = (S == 1) ? (dstp + (size_t)blk * L_)
                          : (dstp + (size_t)b * L_ * N_ + n);
  float2 v[8];
  float lsum = 0.f, lsq = 0.f;
  if (S == 1) {
    const float2* r2 = (const float2*)base;
#pragma unroll
    for (int r = 0; r < 8; ++r) {
      float2 z = r2[t + 256 * r];
      v[r] = z;
      lsum += z.x + z.y;
      lsq += z.x * z.x + z.y * z.y;
    }
  } else {
#pragma unroll
    for (int r = 0; r < 8; ++r) {
      int k = t + 256 * r;
      float2 z = make_float2(base[(size_t)(2 * k) * S], base[(size_t)(2 * k + 1) * S]);
      v[r] = z;
      lsum += z.x + z.y;
      lsq += z.x * z.x + z.y * z.y;
    }
  }
  // wave shuffle reduce + cross-wave via 12 floats of buf
  for (int off = 32; off > 0; off >>= 1) {
    lsum += __shfl_down(lsum, off);
    lsq += __shfl_down(lsq, off);
  }
  {
    float* rb = (float*)buf;
    int lane = t & 63, wid = t >> 6;
    if (lane == 0) { rb[wid] = lsum; rb[8 + wid] = lsq; }
    __syncthreads();
    if (t == 0) {
      float s1 = rb[0] + rb[1] + rb[2] + rb[3];
      float s2 = rb[8] + rb[9] + rb[10] + rb[11];
      float mean = s1 * (1.0f / 4096.0f);
      float var = s2 * (1.0f / 4096.0f) - mean * mean + 1e-6f;
      sstat[0] = mean;
      sstat[1] = sqrtf(var);
    }
  }
  fft2048<-1>(buf, v, t);  // internal first sync protects rb reads

  float mean = sstat[0], sdv = sstat[1];
  const float* wm = wmask + (size_t)b * F_;

  // spectral filter: thread handles f = t+256*i (i=0..3), paired with 2048-f
  float2 zf_[4], zm_[4];
#pragma unroll
  for (int i = 0; i < 4; ++i) {
    int f = t + 256 * i;
    int fm = (f == 0) ? 1024 : (2048 - f);
    zf_[i] = buf[pidx(f)];
    zm_[i] = buf[pidx(fm)];
  }
  __syncthreads();
#pragma unroll
  for (int i = 0; i < 4; ++i) {
    int f = t + 256 * i;
    if (f == 0) {
      float2 z0 = zf_[0];
      float2 zc = zm_[0];  // Z[1024]
      float X0 = (z0.x + z0.y) * (1.f + sdv * wm[0]);
      float XM = (z0.x - z0.y) * (1.f + sdv * wm[2048]);
      buf[pidx(0)] = make_float2(0.5f * (X0 + XM), 0.5f * (X0 - XM));
      float mc = 1.f + sdv * wm[1024];
      buf[pidx(1024)] = make_float2(zc.x * mc, zc.y * mc);
    } else {
      float2 zf = zf_[i], zm = zm_[i];
      float Are = 0.5f * (zf.x + zm.x), Aim = 0.5f * (zf.y - zm.y);
      float Bre = 0.5f * (zf.y + zm.y), Bim = -0.5f * (zf.x - zm.x);
      float ang = (float)f * 0.00153398078788564117f;  // 2pi f / L
      float sv, cv;
      __sincosf(ang, &sv, &cv);
      float WBre = cv * Bre + sv * Bim;
      float WBim = cv * Bim - sv * Bre;
      float Xre = Are + WBre, Xim = Aim + WBim;
      float Xmre = Are - WBre, Xmim = -(Aim - WBim);
      float mf = 1.f + sdv * wm[f];
      float mg = 1.f + sdv * wm[2048 - f];
      Xre *= mf; Xim *= mf;
      Xmre *= mg; Xmim *= mg;
      float Apre = 0.5f * (Xre + Xmre), Apim = 0.5f * (Xim - Xmim);
      float Tre = 0.5f * (Xre - Xmre), Tim = 0.5f * (Xim + Xmim);
      float Bpre = cv * Tre - sv * Tim;
      float Bpim = cv * Tim + sv * Tre;
      buf[pidx(f)] = make_float2(Apre - Bpim, Apim + Bpre);
      float Agre = 0.5f * (Xmre + Xre), Agim = 0.5f * (Xmim - Xim);
      float Tgre = 0.5f * (Xmre - Xre), Tgim = 0.5f * (Xmim + Xim);
      float Bgre = -(cv * Tgre + sv * Tgim);
      float Bgim = -(cv * Tgim - sv * Tgre);
      buf[pidx(2048 - f)] = make_float2(Agre - Bgim, Agim + Bgre);
    }
  }
  __syncthreads();
#pragma unroll
  for (int r = 0; r < 8; ++r) v[r] = buf[pidx(t + 256 * r)];
  fft2048<1>(buf, v, t);  // unnormalized inverse

  const float inv = 1.0f / 2048.0f;
  if (S == 1) {
    float2* o2 = (float2*)obase;
#pragma unroll
    for (int r = 0; r < 8; ++r) {
      int k = t + 256 * r;
      float2 z = buf[pidx(k)];
      o2[k] = make_float2(z.x * inv + mean, z.y * inv + mean);
    }
  } else {
#pragma unroll
    for (int r = 0; r < 8; ++r) {
      int k = t + 256 * r;
      float2 z = buf[pidx(k)];
      obase[(size_t)(2 * k) * S] = z.x * inv + mean;
      obase[(size_t)(2 * k + 1) * S] = z.y * inv + mean;
    }
  }
}

// ---------------------------------------------------------------------------
extern "C" void kernel_launch(void* const* d_in, const int* in_sizes, int n_in,
                              void* d_out, int out_size, void* d_ws,
                              size_t ws_size, hipStream_t stream) {
  const float* x = (const float*)d_in[0];
  const float* bbs = (const float*)d_in[1];
  const float* W1 = (const float*)d_in[2];
  const float* gb1 = (const float*)d_in[3];
  const float* W2 = (const float*)d_in[4];
  const float* gb2 = (const float*)d_in[5];
  float* out = (float*)d_out;

  const size_t bigElems = (size_t)B_ * N_ * L_;
  const size_t smallBytes = (size_t)3 * B_ * F_ * sizeof(float);
  const bool fast = ws_size >= bigElems * sizeof(float) + smallBytes;

  char* smallBase = (char*)d_ws + (fast ? bigElems * sizeof(float) : 0);
  float* magsum = (float*)smallBase;
  float* hsum = magsum + (size_t)B_ * F_;
  float* wmaskp = hsum + (size_t)B_ * F_;
  float* outT = (float*)d_ws;

  hipMemsetAsync(magsum, 0, (size_t)2 * B_ * F_ * sizeof(float), stream);

  dim3 tb(32, 8);
  if (fast) {
    transpose_k<<<dim3(N_ / 32, L_ / 32, B_), tb, 0, stream>>>(x, out, L_, N_);
    p1_fft_mag<1><<<dim3(B_ * N_), 256, 0, stream>>>(out, magsum);
  } else {
    p1_fft_mag<N_><<<dim3(B_ * N_), 256, 0, stream>>>(x, magsum);
  }
  g1_gemm<<<dim3(17, 16), 128, 0, stream>>>(magsum, W1, hsum);
  g2_gate<<<dim3(B_), 256, 0, stream>>>(hsum, gb1, W2, gb2, bbs, wmaskp);
  if (fast) {
    p3_filter<1><<<dim3(B_ * N_), 256, 0, stream>>>(out, wmaskp, outT);
    transpose_k<<<dim3(L_ / 32, N_ / 32, B_), tb, 0, stream>>>(outT, out, N_, L_);
  } else {
    p3_filter<N_><<<dim3(B_ * N_), 256, 0, stream>>>(x, wmaskp, out);
  }
}